// Round 2
// baseline (284.659 us; speedup 1.0000x reference)
//
#include <hip/hip_runtime.h>

typedef unsigned short u16;
typedef u16 ushort8 __attribute__((ext_vector_type(8)));
typedef __bf16 bf16x8 __attribute__((ext_vector_type(8)));
typedef float f32x4 __attribute__((ext_vector_type(4)));
typedef long long ll;

__device__ __forceinline__ u16 f2bf(float f) {
    unsigned u = __builtin_bit_cast(unsigned, f);
    u += 0x7FFFu + ((u >> 16) & 1u);
    return (u16)(u >> 16);
}
__device__ __forceinline__ float bf2f(u16 h) {
    return __builtin_bit_cast(float, (unsigned)h << 16);
}

// ---------------------------------------------------------------------------
// Effective QKV weights: WT[e][d] = (bf16) sum_h W[(h*512+d)*512 + e]
// ---------------------------------------------------------------------------
__global__ __launch_bounds__(256) void reduce_qkv_w(
    const float* __restrict__ Wq, const float* __restrict__ Wk,
    const float* __restrict__ Wv,
    u16* __restrict__ WqT, u16* __restrict__ WkT, u16* __restrict__ WvT)
{
    int idx = blockIdx.x * 256 + threadIdx.x;   // 0 .. 512*512-1
    int e = idx & 511, d = idx >> 9;
    float sq = 0.f, sk = 0.f, sv = 0.f;
#pragma unroll
    for (int h = 0; h < 8; ++h) {
        ll off = (ll)(h * 512 + d) * 512 + e;
        sq += Wq[off]; sk += Wk[off]; sv += Wv[off];
    }
    int o = e * 512 + d;
    WqT[o] = f2bf(sq); WkT[o] = f2bf(sk); WvT[o] = f2bf(sv);
}

// ---------------------------------------------------------------------------
// fp32 -> bf16 cast, 8 elems/thread
// ---------------------------------------------------------------------------
__global__ __launch_bounds__(256) void cvt_f32_bf16(
    const float* __restrict__ in, u16* __restrict__ out, ll n)
{
    ll i = ((ll)blockIdx.x * 256 + threadIdx.x) * 8;
    if (i >= n) return;
    float4 a = *(const float4*)&in[i];
    float4 b = *(const float4*)&in[i + 4];
    ushort8 o;
    o[0] = f2bf(a.x); o[1] = f2bf(a.y); o[2] = f2bf(a.z); o[3] = f2bf(a.w);
    o[4] = f2bf(b.x); o[5] = f2bf(b.y); o[6] = f2bf(b.z); o[7] = f2bf(b.w);
    *(ushort8*)&out[i] = o;
}

// ---------------------------------------------------------------------------
// 64x64 LDS transpose: out[c][r] = bf16(in[r][c]); in is R x C
// grid: (R/64, C/64, batch)
// ---------------------------------------------------------------------------
template<bool SRC_F32>
__global__ __launch_bounds__(256) void transpose_k(
    const void* __restrict__ in, u16* __restrict__ out,
    int R, int C, ll inB, ll outB)
{
    __shared__ u16 tile[64][65];
    int b = blockIdx.z;
    int r0 = blockIdx.x * 64, c0 = blockIdx.y * 64;
#pragma unroll
    for (int i = 0; i < 16; ++i) {
        int lin = threadIdx.x + i * 256;
        int rr = lin >> 6, cc = lin & 63;
        ll src = (ll)b * inB + (ll)(r0 + rr) * C + (c0 + cc);
        u16 val = SRC_F32 ? f2bf(((const float*)in)[src]) : ((const u16*)in)[src];
        tile[rr][cc] = val;
    }
    __syncthreads();
#pragma unroll
    for (int i = 0; i < 16; ++i) {
        int lin = threadIdx.x + i * 256;
        int rr = lin >> 6, cc = lin & 63;   // rr over C-dim, cc over R-dim
        out[(ll)b * outB + (ll)(c0 + rr) * R + (r0 + cc)] = tile[cc][rr];
    }
}

// ---------------------------------------------------------------------------
// Generic bf16 MFMA GEMM: C[M,N] = alpha * A[M,K] @ Bt[N,K]^T + bias[N]
// A, Bt bf16; C fp32 or bf16.  M%128==0, N%128==0, K%32==0.
// 256 threads = 4 waves (2x2), each wave 64x64 out = 4x4 frags of 16x16x32.
// grid: (M/128, N/128, batch)
// ---------------------------------------------------------------------------
template<bool OUT_BF16>
__global__ __launch_bounds__(256) void gemm_bt(
    const u16* __restrict__ A, const u16* __restrict__ Bt,
    void* __restrict__ C, const float* __restrict__ bias,
    int M, int N, int K, float alpha,
    ll strideA, ll strideB, ll strideC)
{
    __shared__ __attribute__((aligned(16))) u16 smA[128 * 32];
    __shared__ __attribute__((aligned(16))) u16 smB[128 * 32];

    const int b = blockIdx.z;
    A += (ll)b * strideA;
    Bt += (ll)b * strideB;
    const int bm = blockIdx.x * 128;
    const int bn = blockIdx.y * 128;
    const int t = threadIdx.x;
    const int w = t >> 6, l = t & 63;
    const int wm = (w >> 1) * 64, wn = (w & 1) * 64;
    const int lr = l & 15, lg = l >> 4;
    const int lk = lg * 8;

    const int srow = t >> 2;          // 0..63
    const int scol = (t & 3) * 8;     // 0,8,16,24

    f32x4 acc[4][4] = {};

    for (int k0 = 0; k0 < K; k0 += 32) {
        // stage 128x32 A and B tiles (2 rounds of 64 rows, 16B per thread)
        ulonglong2 va0 = *(const ulonglong2*)&A[(ll)(bm + srow) * K + k0 + scol];
        ulonglong2 vb0 = *(const ulonglong2*)&Bt[(ll)(bn + srow) * K + k0 + scol];
        ulonglong2 va1 = *(const ulonglong2*)&A[(ll)(bm + 64 + srow) * K + k0 + scol];
        ulonglong2 vb1 = *(const ulonglong2*)&Bt[(ll)(bn + 64 + srow) * K + k0 + scol];
        *(ulonglong2*)&smA[srow * 32 + scol] = va0;
        *(ulonglong2*)&smB[srow * 32 + scol] = vb0;
        *(ulonglong2*)&smA[(64 + srow) * 32 + scol] = va1;
        *(ulonglong2*)&smB[(64 + srow) * 32 + scol] = vb1;
        __syncthreads();

        bf16x8 af[4], bfr[4];
#pragma unroll
        for (int i = 0; i < 4; ++i)
            af[i] = *(const bf16x8*)&smA[(wm + i * 16 + lr) * 32 + lk];
#pragma unroll
        for (int i = 0; i < 4; ++i)
            bfr[i] = *(const bf16x8*)&smB[(wn + i * 16 + lr) * 32 + lk];
#pragma unroll
        for (int mi = 0; mi < 4; ++mi)
#pragma unroll
            for (int ni = 0; ni < 4; ++ni)
                acc[mi][ni] = __builtin_amdgcn_mfma_f32_16x16x32_bf16(
                    af[mi], bfr[ni], acc[mi][ni], 0, 0, 0);
        __syncthreads();
    }

    // epilogue: C/D mapping col = lane&15, row = (lane>>4)*4 + j
    const ll cbase = (ll)b * strideC;
#pragma unroll
    for (int ni = 0; ni < 4; ++ni) {
        int col = bn + wn + ni * 16 + lr;
        float bv = bias ? bias[col] : 0.f;
#pragma unroll
        for (int mi = 0; mi < 4; ++mi) {
#pragma unroll
            for (int j = 0; j < 4; ++j) {
                int row = bm + wm + mi * 16 + lg * 4 + j;
                float v = acc[mi][ni][j] * alpha + bv;
                if (OUT_BF16)
                    ((u16*)C)[cbase + (ll)row * N + col] = f2bf(v);
                else
                    ((float*)C)[cbase + (ll)row * N + col] = v;
            }
        }
    }
}

// ---------------------------------------------------------------------------
// Row softmax: read fp32 logits, write bf16 probabilities (separate buffers).
// Row length 2048, 256 threads x 8 elems.
// ---------------------------------------------------------------------------
__global__ __launch_bounds__(256) void softmax_f2b(
    const float* __restrict__ in, u16* __restrict__ out, int ncols)
{
    ll row = blockIdx.x;
    const float* rp = in + row * (ll)ncols;
    u16* op = out + row * (ll)ncols;
    int t = threadIdx.x;
    float4 a = *(const float4*)&rp[t * 8];
    float4 b = *(const float4*)&rp[t * 8 + 4];
    float v[8] = { a.x, a.y, a.z, a.w, b.x, b.y, b.z, b.w };
    float m = -1e30f;
#pragma unroll
    for (int i = 0; i < 8; ++i) m = fmaxf(m, v[i]);
#pragma unroll
    for (int off = 32; off; off >>= 1) m = fmaxf(m, __shfl_xor(m, off));
    __shared__ float redm[4], reds[4];
    if ((t & 63) == 0) redm[t >> 6] = m;
    __syncthreads();
    m = fmaxf(fmaxf(redm[0], redm[1]), fmaxf(redm[2], redm[3]));
    float s = 0.f;
#pragma unroll
    for (int i = 0; i < 8; ++i) { v[i] = __expf(v[i] - m); s += v[i]; }
#pragma unroll
    for (int off = 32; off; off >>= 1) s += __shfl_xor(s, off);
    if ((t & 63) == 0) reds[t >> 6] = s;
    __syncthreads();
    s = reds[0] + reds[1] + reds[2] + reds[3];
    float inv = 1.f / s;
    ushort8 o;
#pragma unroll
    for (int i = 0; i < 8; ++i) o[i] = f2bf(v[i] * inv);
    *(ushort8*)&op[t * 8] = o;
}

// ---------------------------------------------------------------------------
// out = LayerNorm(a + b) * gamma + beta over rows of 512 (1 wave/row)
// writes fp32 (if outf) and bf16 (if outb)
// ---------------------------------------------------------------------------
__global__ __launch_bounds__(64) void add_ln(
    const float* __restrict__ a, const float* __restrict__ b,
    const float* __restrict__ gamma, const float* __restrict__ beta,
    float* __restrict__ outf, u16* __restrict__ outb)
{
    ll row = blockIdx.x;
    const float* pa = a + row * 512;
    const float* pb = b + row * 512;
    int l = threadIdx.x;
    float4 a0 = *(const float4*)&pa[l * 8], a1 = *(const float4*)&pa[l * 8 + 4];
    float4 b0 = *(const float4*)&pb[l * 8], b1 = *(const float4*)&pb[l * 8 + 4];
    float x[8] = { a0.x + b0.x, a0.y + b0.y, a0.z + b0.z, a0.w + b0.w,
                   a1.x + b1.x, a1.y + b1.y, a1.z + b1.z, a1.w + b1.w };
    float s = 0.f, ss = 0.f;
#pragma unroll
    for (int i = 0; i < 8; ++i) { s += x[i]; ss += x[i] * x[i]; }
#pragma unroll
    for (int off = 32; off; off >>= 1) {
        s += __shfl_xor(s, off);
        ss += __shfl_xor(ss, off);
    }
    float mean = s * (1.f / 512.f);
    float var = ss * (1.f / 512.f) - mean * mean;
    float rs = rsqrtf(var + 1e-14f);
    float o[8];
#pragma unroll
    for (int i = 0; i < 8; ++i)
        o[i] = (x[i] - mean) * rs * gamma[l * 8 + i] + beta[l * 8 + i];
    if (outf) {
        float4 o0 = { o[0], o[1], o[2], o[3] }, o1 = { o[4], o[5], o[6], o[7] };
        *(float4*)&outf[row * 512 + l * 8] = o0;
        *(float4*)&outf[row * 512 + l * 8 + 4] = o1;
    }
    if (outb) {
        ushort8 ob;
#pragma unroll
        for (int i = 0; i < 8; ++i) ob[i] = f2bf(o[i]);
        *(ushort8*)&outb[row * 512 + l * 8] = ob;
    }
}

// ---------------------------------------------------------------------------
extern "C" void kernel_launch(void* const* d_in, const int* in_sizes, int n_in,
                              void* d_out, int out_size, void* d_ws, size_t ws_size,
                              hipStream_t stream)
{
    const float* x      = (const float*)d_in[0];
    const float* Wq     = (const float*)d_in[1];
    const float* bq     = (const float*)d_in[2];
    const float* Wk     = (const float*)d_in[3];
    const float* bk     = (const float*)d_in[4];
    const float* Wv     = (const float*)d_in[5];
    const float* bv     = (const float*)d_in[6];
    const float* gamma1 = (const float*)d_in[7];
    const float* beta1  = (const float*)d_in[8];
    const float* gamma2 = (const float*)d_in[9];
    const float* beta2  = (const float*)d_in[10];
    const float* W1     = (const float*)d_in[11];
    const float* b1     = (const float*)d_in[12];
    const float* W2     = (const float*)d_in[13];
    const float* b2     = (const float*)d_in[14];

    const int B = 4, S = 2048, D = 512, F = 2048;
    const int BS = B * S;  // 8192

    char* w = (char*)d_ws;
    auto alloc = [&](size_t bytes) {
        char* p = w;
        w += (bytes + 255) & ~(size_t)255;
        return p;
    };
    u16* wqT = (u16*)alloc((size_t)D * D * 2);
    u16* wkT = (u16*)alloc((size_t)D * D * 2);
    u16* wvT = (u16*)alloc((size_t)D * D * 2);
    u16* w1T = (u16*)alloc((size_t)F * D * 2);   // [F][D]
    u16* w2T = (u16*)alloc((size_t)D * F * 2);   // [D][F]
    u16* xb  = (u16*)alloc((size_t)BS * D * 2);  // reused as h_bf later
    u16* qb  = (u16*)alloc((size_t)BS * D * 2);  // reused as vT later
    u16* kb  = (u16*)alloc((size_t)BS * D * 2);
    u16* vb  = (u16*)alloc((size_t)BS * D * 2);
    u16* attnb = (u16*)alloc((size_t)B * S * S * 2);        // bf16 probs, 32MB
    float* big = (float*)alloc((size_t)B * S * S * 4);      // 64MB overlay region

    // overlay plan (all writes strictly after fp32 scores are dead):
    float* scoresF = big;                         // [B,S,S] fp32, steps 6-8
    float* y  = big;                              // [BS,D] fp32, step 9+
    float* h  = big + (size_t)BS * D;             // [BS,D] fp32, step 10+
    u16*  f1  = (u16*)(big + (size_t)2 * BS * D); // [BS,F] bf16 (32MB), step 11+
    float* f2 = big;                              // [BS,D] fp32, step 12 (y dead)
    u16* vT = qb;
    u16* hb = xb;

    // 1. effective QKV weights (transposed, bf16)
    reduce_qkv_w<<<dim3(D * D / 256), 256, 0, stream>>>(Wq, Wk, Wv, wqT, wkT, wvT);
    // 2-3. W1T [F][D], W2T [D][F]
    transpose_k<true><<<dim3(D / 64, F / 64, 1), 256, 0, stream>>>(W1, w1T, D, F, 0, 0);
    transpose_k<true><<<dim3(F / 64, D / 64, 1), 256, 0, stream>>>(W2, w2T, F, D, 0, 0);
    // 4. x -> bf16
    cvt_f32_bf16<<<dim3(BS * D / 8 / 256), 256, 0, stream>>>(x, xb, (ll)BS * D);
    // 5. q,k,v = x @ Weff + bias
    gemm_bt<true><<<dim3(BS / 128, D / 128, 1), 256, 0, stream>>>(
        xb, wqT, qb, bq, BS, D, D, 1.f, 0, 0, 0);
    gemm_bt<true><<<dim3(BS / 128, D / 128, 1), 256, 0, stream>>>(
        xb, wkT, kb, bk, BS, D, D, 1.f, 0, 0, 0);
    gemm_bt<true><<<dim3(BS / 128, D / 128, 1), 256, 0, stream>>>(
        xb, wvT, vb, bv, BS, D, D, 1.f, 0, 0, 0);
    // 6. scores = q @ k^T / 8 -> fp32 (keep full logit precision for softmax)
    gemm_bt<false><<<dim3(S / 128, S / 128, B), 256, 0, stream>>>(
        qb, kb, scoresF, nullptr, S, S, D, 0.125f,
        (ll)S * D, (ll)S * D, (ll)S * S);
    // 7. vT[b][e][t] = v[b][t][e]
    transpose_k<false><<<dim3(S / 64, D / 64, B), 256, 0, stream>>>(
        vb, vT, S, D, (ll)S * D, (ll)D * S);
    // 8. softmax: fp32 logits -> bf16 probs
    softmax_f2b<<<dim3(B * S), 256, 0, stream>>>(scoresF, attnb, S);
    // 9. y = attn @ v  (fp32 out; scoresF dead, y overlays it)
    gemm_bt<false><<<dim3(S / 128, D / 128, B), 256, 0, stream>>>(
        attnb, vT, y, nullptr, S, D, S, 1.f,
        (ll)S * S, (ll)D * S, (ll)S * D);
    // 10. h = LN(x + y)  -> fp32 + bf16
    add_ln<<<dim3(BS), 64, 0, stream>>>(x, y, gamma1, beta1, h, hb);
    // 11. f1 = h @ W1 + b1 (bf16)
    gemm_bt<true><<<dim3(BS / 128, F / 128, 1), 256, 0, stream>>>(
        hb, w1T, f1, b1, BS, F, D, 1.f, 0, 0, 0);
    // 12. f2 = f1 @ W2 + b2 (fp32; y dead, f2 overlays it)
    gemm_bt<false><<<dim3(BS / 128, D / 128, 1), 256, 0, stream>>>(
        f1, w2T, f2, b2, BS, D, F, 1.f, 0, 0, 0);
    // 13. out = LN(h + f2)
    add_ln<<<dim3(BS), 64, 0, stream>>>(h, f2, gamma2, beta2, (float*)d_out, nullptr);
}

// Round 3
// 229.420 us; speedup vs baseline: 1.2408x; 1.2408x over previous
//
#include <hip/hip_runtime.h>

typedef unsigned short u16;
typedef u16 ushort8 __attribute__((ext_vector_type(8)));
typedef __bf16 bf16x8 __attribute__((ext_vector_type(8)));
typedef float f32x4 __attribute__((ext_vector_type(4)));
typedef long long ll;

__device__ __forceinline__ u16 f2bf(float f) {
    unsigned u = __builtin_bit_cast(unsigned, f);
    u += 0x7FFFu + ((u >> 16) & 1u);
    return (u16)(u >> 16);
}
__device__ __forceinline__ float bf2f(u16 h) {
    return __builtin_bit_cast(float, (unsigned)h << 16);
}

// async global->LDS, 16B per lane, wave-uniform LDS base + lane*16
#define GLOAD16(dst, src) \
    __builtin_amdgcn_global_load_lds( \
        (const __attribute__((address_space(1))) void*)(src), \
        (__attribute__((address_space(3))) void*)(dst), 16, 0, 0)

// ---------------------------------------------------------------------------
// Effective QKV weights, stacked+transposed: rows 0-511 q, 512-1023 k, 1024+ v
// WqkvT[(sec*512 + e)*512 + d] = bf16( sum_h W[(h*512+d)*512 + e] )
// ---------------------------------------------------------------------------
__global__ __launch_bounds__(256) void reduce_qkv_w(
    const float* __restrict__ Wq, const float* __restrict__ Wk,
    const float* __restrict__ Wv, u16* __restrict__ WqkvT)
{
    int idx = blockIdx.x * 256 + threadIdx.x;   // 0 .. 512*512-1
    int e = idx & 511, d = idx >> 9;
    float sq = 0.f, sk = 0.f, sv = 0.f;
#pragma unroll
    for (int h = 0; h < 8; ++h) {
        ll off = (ll)(h * 512 + d) * 512 + e;
        sq += Wq[off]; sk += Wk[off]; sv += Wv[off];
    }
    int o = e * 512 + d;
    WqkvT[o] = f2bf(sq);
    WqkvT[512 * 512 + o] = f2bf(sk);
    WqkvT[1024 * 512 + o] = f2bf(sv);
}

__global__ __launch_bounds__(256) void concat_bias(
    const float* __restrict__ bq, const float* __restrict__ bk,
    const float* __restrict__ bv, float* __restrict__ bqkv)
{
    int i = blockIdx.x * 256 + threadIdx.x;  // 0..1535
    float v = (i < 512) ? bq[i] : (i < 1024 ? bk[i - 512] : bv[i - 1024]);
    bqkv[i] = v;
}

// ---------------------------------------------------------------------------
// fp32 -> bf16 cast, 8 elems/thread
// ---------------------------------------------------------------------------
__global__ __launch_bounds__(256) void cvt_f32_bf16(
    const float* __restrict__ in, u16* __restrict__ out, ll n)
{
    ll i = ((ll)blockIdx.x * 256 + threadIdx.x) * 8;
    if (i >= n) return;
    float4 a = *(const float4*)&in[i];
    float4 b = *(const float4*)&in[i + 4];
    ushort8 o;
    o[0] = f2bf(a.x); o[1] = f2bf(a.y); o[2] = f2bf(a.z); o[3] = f2bf(a.w);
    o[4] = f2bf(b.x); o[5] = f2bf(b.y); o[6] = f2bf(b.z); o[7] = f2bf(b.w);
    *(ushort8*)&out[i] = o;
}

// ---------------------------------------------------------------------------
// 64x64 LDS transpose: out[c][r] = bf16(in[r][c]); in is R x C (ld = ldin)
// grid: (R/64, C/64, batch)
// ---------------------------------------------------------------------------
template<bool SRC_F32>
__global__ __launch_bounds__(256) void transpose_k(
    const void* __restrict__ in, u16* __restrict__ out,
    int ldin, int ldout, ll inB, ll outB)
{
    __shared__ u16 tile[64][65];
    int b = blockIdx.z;
    int r0 = blockIdx.x * 64, c0 = blockIdx.y * 64;
#pragma unroll
    for (int i = 0; i < 16; ++i) {
        int lin = threadIdx.x + i * 256;
        int rr = lin >> 6, cc = lin & 63;
        ll src = (ll)b * inB + (ll)(r0 + rr) * ldin + (c0 + cc);
        u16 val = SRC_F32 ? f2bf(((const float*)in)[src]) : ((const u16*)in)[src];
        tile[rr][cc] = val;
    }
    __syncthreads();
#pragma unroll
    for (int i = 0; i < 16; ++i) {
        int lin = threadIdx.x + i * 256;
        int rr = lin >> 6, cc = lin & 63;
        out[(ll)b * outB + (ll)(c0 + rr) * ldout + (r0 + cc)] = tile[cc][rr];
    }
}

// ---------------------------------------------------------------------------
// bf16 MFMA GEMM with async LDS staging and optional split-K.
//   C[M,N](+slice) = alpha * A[M,Kslice] @ Bt[N,Kslice]^T + bias[N] (slice 0)
// A/Bt bf16 row-major with lda/ldb; C fp32 or bf16 with ldc.
// grid: (M/128, N/128, batch*nsplit); 256 thr = 4 waves (2x2 of 64x64).
// ---------------------------------------------------------------------------
template<bool OUT_BF16>
__global__ __launch_bounds__(256) void gemm2(
    const u16* __restrict__ A, const u16* __restrict__ Bt,
    void* __restrict__ C, const float* __restrict__ bias,
    int lda, int ldb, int ldc, int Kslice, int nsplit, float alpha,
    ll strideA, ll strideB, ll strideC, ll sliceStrideC)
{
    __shared__ __attribute__((aligned(16))) u16 smA[128 * 32];
    __shared__ __attribute__((aligned(16))) u16 smB[128 * 32];

    const int z = blockIdx.z;
    const int b = z / nsplit, s = z - b * nsplit;
    A  += (ll)b * strideA + (ll)s * Kslice;
    Bt += (ll)b * strideB + (ll)s * Kslice;
    const ll cbase = (ll)b * strideC + (ll)s * sliceStrideC;

    const int bm = blockIdx.x * 128, bn = blockIdx.y * 128;
    const int t = threadIdx.x, w = t >> 6, l = t & 63;
    const int wm = (w >> 1) * 64, wn = (w & 1) * 64;
    const int lr = l & 15, lg = l >> 4;

    // staging geometry: wave w owns rows [w*32, w*32+32) of each 128x32 tile,
    // two 1KiB wave-instructions per tile (16 rows each); lane i covers
    // row i/4, 8-elem chunk i%4 -> matches linear LDS dest base + lane*16.
    const int r0 = w * 32 + (l >> 2);
    const int cs = (l & 3) * 8;
    const u16* ga0 = A + (ll)(bm + r0) * lda + cs;
    const u16* ga1 = A + (ll)(bm + r0 + 16) * lda + cs;
    const u16* gb0 = Bt + (ll)(bn + r0) * ldb + cs;
    const u16* gb1 = Bt + (ll)(bn + r0 + 16) * ldb + cs;
    u16* la0 = &smA[(w * 32) * 32];      // wave-uniform LDS bases
    u16* la1 = &smA[(w * 32 + 16) * 32];
    u16* lb0 = &smB[(w * 32) * 32];
    u16* lb1 = &smB[(w * 32 + 16) * 32];

    f32x4 acc[4][4] = {};

    for (int k0 = 0; k0 < Kslice; k0 += 32) {
        GLOAD16(la0, ga0);
        GLOAD16(la1, ga1);
        GLOAD16(lb0, gb0);
        GLOAD16(lb1, gb1);
        ga0 += 32; ga1 += 32; gb0 += 32; gb1 += 32;
        __syncthreads();   // drains vmcnt(0) -> LDS tiles complete

        bf16x8 af[4], bfr[4];
#pragma unroll
        for (int i = 0; i < 4; ++i)
            af[i] = *(const bf16x8*)&smA[(wm + i * 16 + lr) * 32 + lg * 8];
#pragma unroll
        for (int i = 0; i < 4; ++i)
            bfr[i] = *(const bf16x8*)&smB[(wn + i * 16 + lr) * 32 + lg * 8];
#pragma unroll
        for (int mi = 0; mi < 4; ++mi)
#pragma unroll
            for (int ni = 0; ni < 4; ++ni)
                acc[mi][ni] = __builtin_amdgcn_mfma_f32_16x16x32_bf16(
                    af[mi], bfr[ni], acc[mi][ni], 0, 0, 0);
        __syncthreads();
    }

    // epilogue: C/D mapping col = lane&15, row = (lane>>4)*4 + j
    const bool addb = (bias != nullptr) && (s == 0);
#pragma unroll
    for (int ni = 0; ni < 4; ++ni) {
        const int col = bn + wn + ni * 16 + lr;
        const float bv = addb ? bias[col] : 0.f;
#pragma unroll
        for (int mi = 0; mi < 4; ++mi) {
#pragma unroll
            for (int j = 0; j < 4; ++j) {
                const int row = bm + wm + mi * 16 + lg * 4 + j;
                const ll off = cbase + (ll)row * ldc + col;
                const float v = acc[mi][ni][j] * alpha + bv;
                if (OUT_BF16) ((u16*)C)[off] = f2bf(v);
                else          ((float*)C)[off] = v;
            }
        }
    }
}

// ---------------------------------------------------------------------------
// Row softmax: read fp32 logits, write bf16 probabilities.
// Row length 2048, 256 threads x 8 elems.
// ---------------------------------------------------------------------------
__global__ __launch_bounds__(256) void softmax_f2b(
    const float* __restrict__ in, u16* __restrict__ out, int ncols)
{
    ll row = blockIdx.x;
    const float* rp = in + row * (ll)ncols;
    u16* op = out + row * (ll)ncols;
    int t = threadIdx.x;
    float4 a = *(const float4*)&rp[t * 8];
    float4 b = *(const float4*)&rp[t * 8 + 4];
    float v[8] = { a.x, a.y, a.z, a.w, b.x, b.y, b.z, b.w };
    float m = -1e30f;
#pragma unroll
    for (int i = 0; i < 8; ++i) m = fmaxf(m, v[i]);
#pragma unroll
    for (int off = 32; off; off >>= 1) m = fmaxf(m, __shfl_xor(m, off));
    __shared__ float redm[4], reds[4];
    if ((t & 63) == 0) redm[t >> 6] = m;
    __syncthreads();
    m = fmaxf(fmaxf(redm[0], redm[1]), fmaxf(redm[2], redm[3]));
    float s = 0.f;
#pragma unroll
    for (int i = 0; i < 8; ++i) { v[i] = __expf(v[i] - m); s += v[i]; }
#pragma unroll
    for (int off = 32; off; off >>= 1) s += __shfl_xor(s, off);
    if ((t & 63) == 0) reds[t >> 6] = s;
    __syncthreads();
    s = reds[0] + reds[1] + reds[2] + reds[3];
    float inv = 1.f / s;
    ushort8 o;
#pragma unroll
    for (int i = 0; i < 8; ++i) o[i] = f2bf(v[i] * inv);
    *(ushort8*)&op[t * 8] = o;
}

// ---------------------------------------------------------------------------
// out = LayerNorm(a + b + c) * gamma + beta over rows of 512 (1 wave/row)
// ---------------------------------------------------------------------------
__global__ __launch_bounds__(64) void add_ln3(
    const float* __restrict__ a, const float* __restrict__ b,
    const float* __restrict__ c,
    const float* __restrict__ gamma, const float* __restrict__ beta,
    float* __restrict__ outf, u16* __restrict__ outb)
{
    ll row = blockIdx.x;
    const float* pa = a + row * 512;
    const float* pb = b + row * 512;
    const float* pc = c + row * 512;
    int l = threadIdx.x;
    float4 a0 = *(const float4*)&pa[l * 8], a1 = *(const float4*)&pa[l * 8 + 4];
    float4 b0 = *(const float4*)&pb[l * 8], b1 = *(const float4*)&pb[l * 8 + 4];
    float4 c0 = *(const float4*)&pc[l * 8], c1 = *(const float4*)&pc[l * 8 + 4];
    float x[8] = { a0.x + b0.x + c0.x, a0.y + b0.y + c0.y,
                   a0.z + b0.z + c0.z, a0.w + b0.w + c0.w,
                   a1.x + b1.x + c1.x, a1.y + b1.y + c1.y,
                   a1.z + b1.z + c1.z, a1.w + b1.w + c1.w };
    float s = 0.f, ss = 0.f;
#pragma unroll
    for (int i = 0; i < 8; ++i) { s += x[i]; ss += x[i] * x[i]; }
#pragma unroll
    for (int off = 32; off; off >>= 1) {
        s += __shfl_xor(s, off);
        ss += __shfl_xor(ss, off);
    }
    float mean = s * (1.f / 512.f);
    float var = ss * (1.f / 512.f) - mean * mean;
    float rs = rsqrtf(var + 1e-14f);
    float o[8];
#pragma unroll
    for (int i = 0; i < 8; ++i)
        o[i] = (x[i] - mean) * rs * gamma[l * 8 + i] + beta[l * 8 + i];
    if (outf) {
        float4 o0 = { o[0], o[1], o[2], o[3] }, o1 = { o[4], o[5], o[6], o[7] };
        *(float4*)&outf[row * 512 + l * 8] = o0;
        *(float4*)&outf[row * 512 + l * 8 + 4] = o1;
    }
    if (outb) {
        ushort8 ob;
#pragma unroll
        for (int i = 0; i < 8; ++i) ob[i] = f2bf(o[i]);
        *(ushort8*)&outb[row * 512 + l * 8] = ob;
    }
}

// ---------------------------------------------------------------------------
extern "C" void kernel_launch(void* const* d_in, const int* in_sizes, int n_in,
                              void* d_out, int out_size, void* d_ws, size_t ws_size,
                              hipStream_t stream)
{
    const float* x      = (const float*)d_in[0];
    const float* Wq     = (const float*)d_in[1];
    const float* bq     = (const float*)d_in[2];
    const float* Wk     = (const float*)d_in[3];
    const float* bk     = (const float*)d_in[4];
    const float* Wv     = (const float*)d_in[5];
    const float* bv     = (const float*)d_in[6];
    const float* gamma1 = (const float*)d_in[7];
    const float* beta1  = (const float*)d_in[8];
    const float* gamma2 = (const float*)d_in[9];
    const float* beta2  = (const float*)d_in[10];
    const float* W1     = (const float*)d_in[11];
    const float* b1     = (const float*)d_in[12];
    const float* W2     = (const float*)d_in[13];
    const float* b2     = (const float*)d_in[14];

    const int B = 4, S = 2048, D = 512, F = 2048;
    const int BS = B * S;  // 8192

    char* w = (char*)d_ws;
    auto alloc = [&](size_t bytes) {
        char* p = w;
        w += (bytes + 255) & ~(size_t)255;
        return p;
    };
    u16* wqkvT = (u16*)alloc((size_t)3 * D * D * 2);   // [1536][512] bf16
    float* bqkv = (float*)alloc((size_t)3 * D * 4);
    u16* w1T = (u16*)alloc((size_t)F * D * 2);         // [F][D]
    u16* w2T = (u16*)alloc((size_t)D * F * 2);         // [D][F]
    u16* xb  = (u16*)alloc((size_t)BS * D * 2);        // reused as hb
    u16* qkvb = (u16*)alloc((size_t)BS * 3 * D * 2);   // [BS][1536]
    u16* attnb = (u16*)alloc((size_t)B * S * S * 2);   // 32MB; reused as f1
    float* big = (float*)alloc((size_t)B * S * S * 4); // 64MB overlay region

    // overlay plan inside `big` (scoresF dead after softmax):
    float* scoresF = big;                              // [B,S,S]    steps 6-7
    float* y0 = big;                                   // [BS,D]     step 9+
    float* y1 = big + (size_t)BS * D;                  // [BS,D]
    float* h  = big + (size_t)2 * BS * D;              // [BS,D]     step 10+
    u16* vT   = (u16*)((char*)big + (size_t)48 * 1024 * 1024);  // [B,D,S] 8MB
    float* f0 = y0;                                    // FFN2 partials (y dead)
    float* f1p = y1;
    u16* hb = xb;
    u16* f1 = attnb;                                   // [BS,F] bf16 (attn dead)

    // 1. effective QKV weights (stacked/transposed) + bias concat
    reduce_qkv_w<<<dim3(D * D / 256), 256, 0, stream>>>(Wq, Wk, Wv, wqkvT);
    concat_bias<<<dim3(6), 256, 0, stream>>>(bq, bk, bv, bqkv);
    // 2-3. W1T [F][D], W2T [D][F]
    transpose_k<true><<<dim3(D / 64, F / 64, 1), 256, 0, stream>>>(
        W1, w1T, F, D, 0, 0);
    transpose_k<true><<<dim3(F / 64, D / 64, 1), 256, 0, stream>>>(
        W2, w2T, D, F, 0, 0);
    // 4. x -> bf16
    cvt_f32_bf16<<<dim3(BS * D / 8 / 256), 256, 0, stream>>>(x, xb, (ll)BS * D);
    // 5. fused qkv = x @ Wqkv^T + bqkv  -> [BS][1536]
    gemm2<true><<<dim3(BS / 128, 3 * D / 128, 1), 256, 0, stream>>>(
        xb, wqkvT, qkvb, bqkv, D, D, 3 * D, D, 1, 1.f, 0, 0, 0, 0);
    // 6. scores = q @ k^T / 8 -> fp32
    gemm2<false><<<dim3(S / 128, S / 128, B), 256, 0, stream>>>(
        qkvb, qkvb + D, scoresF, nullptr, 3 * D, 3 * D, S, D, 1, 0.125f,
        (ll)S * 3 * D, (ll)S * 3 * D, (ll)S * S, 0);
    // 7. softmax: fp32 logits -> bf16 probs
    softmax_f2b<<<dim3(B * S), 256, 0, stream>>>(scoresF, attnb, S);
    // 8. vT[b][e][t] = v[b][t][e]   (scoresF dead; vT lives at big+48MB)
    transpose_k<false><<<dim3(S / 64, D / 64, B), 256, 0, stream>>>(
        qkvb + 2 * D, vT, 3 * D, S, (ll)S * 3 * D, (ll)D * S);
    // 9. y = attn @ v, split-K=2 -> fp32 partials y0,y1
    gemm2<false><<<dim3(S / 128, D / 128, B * 2), 256, 0, stream>>>(
        attnb, vT, y0, nullptr, S, S, D, S / 2, 2, 1.f,
        (ll)S * S, (ll)D * S, (ll)S * D, (ll)BS * D);
    // 10. h = LN(x + y0 + y1) -> fp32 + bf16
    add_ln3<<<dim3(BS), 64, 0, stream>>>(x, y0, y1, gamma1, beta1, h, hb);
    // 11. f1 = h @ W1 + b1 (bf16; overlays attnb)
    gemm2<true><<<dim3(BS / 128, F / 128, 1), 256, 0, stream>>>(
        hb, w1T, f1, b1, D, D, F, D, 1, 1.f, 0, 0, 0, 0);
    // 12. f2 = f1 @ W2 + b2, split-K=2 -> fp32 partials f0,f1p (y dead)
    gemm2<false><<<dim3(BS / 128, D / 128, 2), 256, 0, stream>>>(
        f1, w2T, f0, b2, F, F, D, F / 2, 2, 1.f, 0, 0, 0, (ll)BS * D);
    // 13. out = LN(h + f0 + f1p)
    add_ln3<<<dim3(BS), 64, 0, stream>>>(h, f0, f1p, gamma2, beta2,
                                         (float*)d_out, nullptr);
}